// Round 6
// baseline (1531.324 us; speedup 1.0000x reference)
//
#include <hip/hip_runtime.h>

// Bidirectional GRU (Keras reset_after) B=32,T=128,E=512,U=1024.
// embed-cast -> weight transposes -> x_proj GEMM -> persistent recurrent kernel
// organized as 8 clusters (2 dirs x 4 batch-quarters), cluster = blockIdx&7 so
// round-robin dispatch puts each cluster on one XCD. Startup VERIFIES sc0
// (XCD-L2) coherence with a bounded ping-pong; on success the epoch-tagged h
// exchange runs through the local L2 (sc0), else falls back to the proven
// device-scope (sc0 sc1) protocol. All spins bounded or provably-terminating.

using u16 = unsigned short;
using u32 = unsigned int;
typedef __attribute__((ext_vector_type(8))) short bfx8;
typedef __attribute__((ext_vector_type(4))) float f32x4;
typedef __attribute__((ext_vector_type(4))) u32 u32x4;
typedef __attribute__((ext_vector_type(3))) u32 u32x3;

#define B_ 32
#define T_ 128
#define E_ 512
#define U_ 1024
#define NG 3072
#define M_ 4096
#define YN 4194304
// Per-cluster Hx: 3 rotations x [8 rows][256 units] x 16B
// unit = {4x bf16 h (8B), u32 epoch tag, 4B pad}
#define ROTB 32768
#define CLB  98304

__device__ __forceinline__ float bf2f(u16 u) {
  union { u32 i; float f; } v; v.i = (u32)u << 16; return v.f;
}
__device__ __forceinline__ u16 f2bf(float f) {
  union { float f; u32 i; } v; v.f = f;
  u32 r = v.i + 0x7FFFu + ((v.i >> 16) & 1u);
  return (u16)(r >> 16);
}
__device__ __forceinline__ float sigm(float x) { return 1.0f / (1.0f + __expf(-x)); }

__device__ __forceinline__ void load_lds16(const void* g, void* l) {
  __builtin_amdgcn_global_load_lds(
      (const __attribute__((address_space(1))) u32*)g,
      (__attribute__((address_space(3))) u32*)l, 16, 0, 0);
}

// ---------------- P1: embedding gather + cast ----------------
__global__ __launch_bounds__(256) void k_embed(const int* __restrict__ tok,
                                               const float* __restrict__ emb,
                                               u16* __restrict__ X) {
  int idx = blockIdx.x * 256 + threadIdx.x;
  int m = idx >> 6, k8 = (idx & 63) << 3;
  int b = m & 31, t = m >> 5;
  int tk = tok[b * T_ + t];
  const float* s = emb + (size_t)tk * E_ + k8;
  float4 v0 = *(const float4*)s, v1 = *(const float4*)(s + 4);
  bfx8 r;
  r[0]=(short)f2bf(v0.x); r[1]=(short)f2bf(v0.y); r[2]=(short)f2bf(v0.z); r[3]=(short)f2bf(v0.w);
  r[4]=(short)f2bf(v1.x); r[5]=(short)f2bf(v1.y); r[6]=(short)f2bf(v1.z); r[7]=(short)f2bf(v1.w);
  *(bfx8*)(X + (size_t)m * E_ + k8) = r;
}

// ---------------- P2: transpose/cast weights ----------------
__global__ void k_transpose(const float* __restrict__ in, u16* __restrict__ out,
                            int K, int N, int remap) {
  __shared__ float tile[32][33];
  int k0 = blockIdx.x * 32, n0 = blockIdx.y * 32;
  int tx = threadIdx.x, ty = threadIdx.y;
  for (int j = ty; j < 32; j += 8) tile[j][tx] = in[(size_t)(k0 + j) * N + n0 + tx];
  __syncthreads();
  for (int j = ty; j < 32; j += 8) {
    int n = n0 + j;
    int row = remap ? ((((n & 1023) >> 5) * 96) + ((n >> 10) << 5) + (n & 31)) : n;
    out[(size_t)row * K + k0 + tx] = f2bf(tile[tx][j]);
  }
}

// ---------------- G: x_proj GEMM ----------------
__global__ __launch_bounds__(256) void k_xproj(const u16* __restrict__ X,
                                               const u16* __restrict__ WT,
                                               const float* __restrict__ biasF,
                                               const float* __restrict__ biasB,
                                               u16* __restrict__ XP) {
  const int n0 = blockIdx.x * 128, m0 = blockIdx.y * 128, dir = blockIdx.z;
  const float* bias = dir ? biasB : biasF;
  const u16* Wd = WT + (size_t)dir * NG * E_;
  __shared__ __align__(16) u16 As[128 * 64];
  __shared__ __align__(16) u16 Bs[128 * 64];
  const int tid = threadIdx.x;
  const int wave = tid >> 6, lane = tid & 63;
  const int moff = (wave >> 1) * 64, noff = (wave & 1) * 64;
  const int l15 = lane & 15, l4 = lane >> 4;
  f32x4 acc[4][4] = {};
  for (int kt = 0; kt < 8; ++kt) {
    int k0 = kt * 64;
#pragma unroll
    for (int j = 0; j < 4; ++j) {
      int o = j * 4096 + tid * 16;
      int row = o >> 7;
      int kk = (((o & 127) ^ ((row & 7) << 4)) >> 1);
      load_lds16(X  + (size_t)(m0 + row) * E_ + k0 + kk, (char*)As + o);
      load_lds16(Wd + (size_t)(n0 + row) * E_ + k0 + kk, (char*)Bs + o);
    }
    __syncthreads();
#pragma unroll
    for (int Ks = 0; Ks < 2; ++Ks) {
      bfx8 a[4], b[4];
#pragma unroll
      for (int Mt = 0; Mt < 4; ++Mt) {
        int ra = moff + Mt * 16 + l15;
        int ba = (ra << 7) + ((Ks * 32 + l4 * 8) << 1);
        ba ^= (ra & 7) << 4;
        a[Mt] = *(const bfx8*)((const char*)As + ba);
      }
#pragma unroll
      for (int Nt = 0; Nt < 4; ++Nt) {
        int rb = noff + Nt * 16 + l15;
        int bb2 = (rb << 7) + ((Ks * 32 + l4 * 8) << 1);
        bb2 ^= (rb & 7) << 4;
        b[Nt] = *(const bfx8*)((const char*)Bs + bb2);
      }
#pragma unroll
      for (int Mt = 0; Mt < 4; ++Mt)
#pragma unroll
        for (int Nt = 0; Nt < 4; ++Nt)
          acc[Mt][Nt] = __builtin_amdgcn_mfma_f32_16x16x32_bf16(a[Mt], b[Nt], acc[Mt][Nt], 0, 0, 0);
    }
    __syncthreads();
  }
  float bv[4];
#pragma unroll
  for (int Nt = 0; Nt < 4; ++Nt) bv[Nt] = bias[n0 + noff + Nt * 16 + l15];
#pragma unroll
  for (int Mt = 0; Mt < 4; ++Mt)
#pragma unroll
    for (int Nt = 0; Nt < 4; ++Nt)
#pragma unroll
      for (int r = 0; r < 4; ++r) {
        int m = m0 + moff + Mt * 16 + l4 * 4 + r;
        int n = n0 + noff + Nt * 16 + l15;
        XP[((size_t)dir * M_ + m) * NG + n] = f2bf(acc[Mt][Nt][r] + bv[Nt]);
      }
}

// ---------------- R: persistent recurrent kernel ----------------
#define BLD(OFF, DST, SC) asm volatile("global_load_dwordx3 %0, %1, off offset:" #OFF " " SC : "=v"(DST) : "v"(a));
#define BLD16(SC) \
  BLD(0,L[0][0],SC)   BLD(16,L[0][1],SC)  BLD(128,L[1][0],SC) BLD(144,L[1][1],SC) \
  BLD(256,L[2][0],SC) BLD(272,L[2][1],SC) BLD(384,L[3][0],SC) BLD(400,L[3][1],SC) \
  BLD(512,L[4][0],SC) BLD(528,L[4][1],SC) BLD(640,L[5][0],SC) BLD(656,L[5][1],SC) \
  BLD(768,L[6][0],SC) BLD(784,L[6][1],SC) BLD(896,L[7][0],SC) BLD(912,L[7][1],SC)
#define LD_SYS(dst, ad) asm volatile("global_load_dword %0, %1, off sc0 sc1\n\ts_waitcnt vmcnt(0)" : "=v"(dst) : "v"(ad) : "memory");
#define LD_L2(dst, ad)  asm volatile("global_load_dword %0, %1, off sc0\n\ts_waitcnt vmcnt(0)" : "=v"(dst) : "v"(ad) : "memory");
#define ST_SYS(ad, vl)  asm volatile("global_store_dword %0, %1, off sc0 sc1" :: "v"(ad), "v"(vl) : "memory");
#define ST_L2(ad, vl)   asm volatile("global_store_dword %0, %1, off sc0" :: "v"(ad), "v"(vl) : "memory");

__global__ __launch_bounds__(256, 1) void k_gru(
    const u16* __restrict__ RW,
    u16* __restrict__ XP,
    const float* __restrict__ bf_, const float* __restrict__ bb_,
    char* __restrict__ comm,
    float* __restrict__ out) {
  const int tid = threadIdx.x;
  const int wave = tid >> 6, lane = tid & 63;
  const int l15 = lane & 15, l4 = lane >> 4;
  const int wg = blockIdx.x;
  const int cl = wg & 7, role = wg >> 3;         // cluster = XCD under round-robin
  const int dir = cl & 1, bq = cl >> 1;
  const int u0 = role * 32;
  __shared__ float pl[4][8][96];
  __shared__ int sh_mode;

  u32* xslot = (u32*)comm;                        // [256] @ 0
  u32* pingp = (u32*)(comm + 1024) + cl * 16;     // 64B-strided per cluster
  u32* ackp  = (u32*)(comm + 1536) + cl * 16;
  u32* modep = (u32*)(comm + 2048) + cl * 16;
  char* Hc   = comm + 4096 + cl * CLB;

  // ---- issue long-latency preloads first (overlap with startup spins) ----
  const u16* wbase = RW + (size_t)dir * NG * U_ + (size_t)role * 96 * U_;
  bfx8 wf[6][8];
#pragma unroll
  for (int nt = 0; nt < 6; ++nt)
#pragma unroll
    for (int ks = 0; ks < 8; ++ks)
      wf[nt][ks] = *(const bfx8*)(wbase + (size_t)(nt * 16 + l15) * U_ + wave * 256 + ks * 32 + l4 * 8);

  const int row = tid >> 5, cli = tid & 31;       // thread owns (row, col u0+cli)
  const int brow = bq * 8 + row;
  const float* b1p = (dir ? bb_ : bf_) + NG;
  float b10 = b1p[u0 + cli], b11 = b1p[U_ + u0 + cli], b12 = b1p[2 * U_ + u0 + cli];
  u16* xpd = XP + (size_t)dir * M_ * NG;
  u16 xc0, xc1, xc2;
  {
    int t0 = dir ? 127 : 0;
    const u16* xr = xpd + (size_t)(t0 * 32 + brow) * NG + u0 + cli;
    xc0 = xr[0]; xc1 = xr[U_]; xc2 = xr[2 * U_];
  }

  // ---- startup: post XCC, verify sc0 (XCD-L2) coherence, pick mode ----
  if (tid == 0) {
    u32 xcc = ((u32)__builtin_amdgcn_s_getreg(6164)) & 15u;  // HW_REG_XCC_ID
    u32 pv = xcc + 1u;
    ST_SYS(&xslot[wg], pv);
    if (role == 1) {
      u32 c1 = 0xC0FFEEu;
      ST_L2(pingp, c1);
      int g = 0;
      while (1) {                                  // ack comes via IF (always correct)
        u32 av; LD_SYS(av, ackp);
        if (av || ++g > (1 << 22)) break;
        __builtin_amdgcn_s_sleep(2);
      }
      u32 c2 = 0xFEED00u;
      ST_L2(pingp, c2);
    }
    u32 m = 0;
    if (role == 0) {
      bool uni = true; u32 x0 = 0;
      int g = 0;
      for (int r = 0; r < 32; ++r) {
        u32 v = 0;
        while (1) {
          LD_SYS(v, &xslot[r * 8 + cl]);
          if (v || ++g > (1 << 22)) break;
          __builtin_amdgcn_s_sleep(2);
        }
        if (!v) uni = false;
        else if (r == 0) x0 = v;
        else uni &= (v == x0);
      }
      m = 2;
      if (uni) {
        bool s1 = false, s2 = false;
        for (int i = 0; i < 8000 && !s1; ++i) {
          u32 v; LD_L2(v, pingp);
          s1 = (v == 0xC0FFEEu);
          if (!s1) __builtin_amdgcn_s_sleep(2);
        }
        u32 one = 1u;
        ST_SYS(ackp, one);                         // always release role1
        if (s1) {
          for (int i = 0; i < 8000 && !s2; ++i) {  // same-line re-read freshness
            u32 v; LD_L2(v, pingp);
            s2 = (v == 0xFEED00u);
            if (!s2) __builtin_amdgcn_s_sleep(2);
          }
        }
        if (s1 && s2) m = 1;
      }
      ST_SYS(modep, m);
    }
    {
      int g = 0;
      while (1) {
        LD_SYS(m, modep);
        if (m || ++g > (1 << 22)) break;
        __builtin_amdgcn_s_sleep(2);
      }
      if (!m) m = 2;
    }
    if (role == 1) { u32 dd = 0xDEAD01u; ST_L2(pingp, dd); }  // stale-proof sentinel
    sh_mode = (int)m;
  }
  __syncthreads();
  const int l2m = (sh_mode == 1);

  float hl = 0.f;
  const int boff = l15 * 4096 + wave * 1024 + l4 * 32;          // consumer bulk base
  const int soff = (row * 256 + role * 8 + (cli >> 2)) * 16;    // producer unit

  int rl = 0, rs = 1;
  for (int e = 0; e < 128; ++e) {
    f32x4 acc[6] = {};
    if (e > 0) {
      const u32 etag = (u32)e;
      char* rbase = Hc + rl * ROTB;
      u32x3 L[8][2];
      int guard = 0;
      while (1) {                      // self-validating bulk: load IS the gate
        u32 bad = 0;
        if (l15 < 8) {
          const char* a = rbase + boff;
          if (l2m) { BLD16("sc0") } else { BLD16("sc0 sc1") }
          asm volatile("s_waitcnt vmcnt(0)");
#pragma unroll
          for (int ks = 0; ks < 8; ++ks)
            asm volatile("" : "+v"(L[ks][0]), "+v"(L[ks][1]));
#pragma unroll
          for (int ks = 0; ks < 8; ++ks)
            bad |= (L[ks][0].z ^ etag) | (L[ks][1].z ^ etag);
        }
        if (__all((int)(bad == 0))) break;
        if (++guard > (1 << 21)) break;            // fail visibly, never hang
        __builtin_amdgcn_s_sleep(1);
      }
      bfx8 af[8] = {};
      if (l15 < 8) {
#pragma unroll
        for (int ks = 0; ks < 8; ++ks) {
          u32x4 fv = {L[ks][0].x, L[ks][0].y, L[ks][1].x, L[ks][1].y};
          af[ks] = __builtin_bit_cast(bfx8, fv);
        }
      }
      __builtin_amdgcn_sched_barrier(0);
#pragma unroll
      for (int ks = 0; ks < 8; ++ks)
#pragma unroll
        for (int nt = 0; nt < 6; ++nt)
          acc[nt] = __builtin_amdgcn_mfma_f32_16x16x32_bf16(af[ks], wf[nt][ks], acc[nt], 0, 0, 0);
    }
    // prefetch next step's x AFTER the gate (HBM latency never inside the spin)
    u16 xn0 = xc0, xn1 = xc1, xn2 = xc2;
    if (e < 127) {
      int tn = dir ? (126 - e) : (e + 1);
      const u16* xr = xpd + (size_t)(tn * 32 + brow) * NG + u0 + cli;
      xn0 = xr[0]; xn1 = xr[U_]; xn2 = xr[2 * U_];
    }
    // dump partials (C rows 0..7): col=lane&15, row=(lane>>4)*4+r
    if (l4 < 2) {
#pragma unroll
      for (int nt = 0; nt < 6; ++nt)
#pragma unroll
        for (int r = 0; r < 4; ++r)
          pl[wave][l4 * 4 + r][nt * 16 + l15] = acc[nt][r];
    }
    __syncthreads();
    // deferred y for epoch e-1 (hl pre-update). Safe: the 4 waves' gates union
    // over all 32 cluster slices => everyone consumed XP row t(e-1) already.
    if (e > 0) {
      int tp = dir ? (128 - e) : (e - 1);
      ((float*)(xpd + (size_t)(tp * 32 + brow) * NG))[u0 + cli] = hl;
    }
    // reduce K-quarters + gates (1 h per thread)
    float red0 = pl[0][row][cli]      + pl[1][row][cli]      + pl[2][row][cli]      + pl[3][row][cli];
    float red1 = pl[0][row][32 + cli] + pl[1][row][32 + cli] + pl[2][row][32 + cli] + pl[3][row][32 + cli];
    float red2 = pl[0][row][64 + cli] + pl[1][row][64 + cli] + pl[2][row][64 + cli] + pl[3][row][64 + cli];
    float z  = sigm(bf2f(xc0) + red0 + b10);
    float r  = sigm(bf2f(xc1) + red1 + b11);
    float hh = tanhf(bf2f(xc2) + r * (red2 + b12));
    hl = z * hl + (1.f - z) * hh;
    // pack 4 lanes' h into one 12B unit + publish (single store, no drain)
    if (e < 127) {
      u32 hb = f2bf(hl);
      u32 o1 = __shfl_xor(hb, 1);
      u32 p = (lane & 1) ? (o1 | (hb << 16)) : (hb | (o1 << 16));
      u32 q = __shfl_xor(p, 2);
      if ((lane & 3) == 0) {
        u32x3 sv; sv.x = p; sv.y = q; sv.z = (u32)(e + 1);
        char* sa = Hc + rs * ROTB + soff;
        if (l2m) asm volatile("global_store_dwordx3 %0, %1, off sc0" :: "v"(sa), "v"(sv) : "memory");
        else     asm volatile("global_store_dwordx3 %0, %1, off sc0 sc1" :: "v"(sa), "v"(sv) : "memory");
      }
    }
    rl = rs; rs = (rs == 2) ? 0 : rs + 1;
    xc0 = xn0; xc1 = xn1; xc2 = xn2;
    __syncthreads();
  }
  // final y row + states. No wait needed: passing gate 127 proved every peer
  // finished epoch 126, which includes their prefetch of row t=127's x.
  {
    int tl = dir ? 0 : 127;
    ((float*)(xpd + (size_t)(tl * 32 + brow) * NG))[u0 + cli] = hl;
    out[YN + (size_t)dir * (B_ * U_) + (size_t)brow * U_ + u0 + cli] = hl;
  }
}

// ---------------- M: y merge  out = yf + yb ----------------
__global__ __launch_bounds__(256) void k_merge(const u16* __restrict__ XP,
                                               float* __restrict__ out) {
  int idx = blockIdx.x * 256 + threadIdx.x;
  int u4 = (idx & 255) * 4;
  int m = idx >> 8;                            // t*32+b
  int t = m >> 5, b = m & 31;
  const float* yf = (const float*)(XP + (size_t)m * NG);
  const float* yb = (const float*)(XP + (size_t)(M_ + m) * NG);
  float4 a = *(const float4*)(yf + u4);
  float4 c = *(const float4*)(yb + u4);
  float4 o; o.x = a.x + c.x; o.y = a.y + c.y; o.z = a.z + c.z; o.w = a.w + c.w;
  *(float4*)(out + ((size_t)b * T_ + t) * U_ + u4) = o;
}

extern "C" void kernel_launch(void* const* d_in, const int* in_sizes, int n_in,
                              void* d_out, int out_size, void* d_ws, size_t ws_size,
                              hipStream_t stream) {
  const int*   tokens = (const int*)d_in[0];
  const float* emb    = (const float*)d_in[1];
  const float* kf     = (const float*)d_in[2];
  const float* rkf    = (const float*)d_in[3];
  const float* bf_    = (const float*)d_in[4];
  const float* kb     = (const float*)d_in[5];
  const float* rkb    = (const float*)d_in[6];
  const float* bb_    = (const float*)d_in[7];
  float* out = (float*)d_out;
  char* ws = (char*)d_ws;

  // workspace layout. comm ALIASES WT (WT dead after k_xproj; memset is
  // stream-ordered after k_xproj, before k_gru). Rot-buffer staleness is
  // provably harmless (tag-order invariant), so only the 4KB header is cleared.
  u16*  X    = (u16*)ws;                      // 4 MB
  u16*  WT   = (u16*)(ws + 0x400000);         // 6 MB
  char* comm = ws + 0x400000;                 // 4KB hdr + 8*96KB Hx (aliases WT)
  u16*  RW   = (u16*)(ws + 0xA00000);         // 12 MB
  u16*  XP   = (u16*)(ws + 0x1600000);        // 48 MB (y stashed in row heads)

  k_embed<<<1024, 256, 0, stream>>>(tokens, emb, X);
  k_transpose<<<dim3(16, 96), dim3(32, 8), 0, stream>>>(kf,  WT,               512,  NG, 0);
  k_transpose<<<dim3(16, 96), dim3(32, 8), 0, stream>>>(kb,  WT + 3072 * 512,  512,  NG, 0);
  k_transpose<<<dim3(32, 96), dim3(32, 8), 0, stream>>>(rkf, RW,               1024, NG, 1);
  k_transpose<<<dim3(32, 96), dim3(32, 8), 0, stream>>>(rkb, RW + 3072 * 1024, 1024, NG, 1);
  k_xproj<<<dim3(24, 32, 2), 256, 0, stream>>>(X, WT, bf_, bb_, XP);
  hipMemsetAsync(comm, 0, 4096, stream);      // clear header (xcc/ping/ack/mode)
  k_gru<<<256, 256, 0, stream>>>(RW, XP, bf_, bb_, comm, out);
  k_merge<<<4096, 256, 0, stream>>>(XP, out);
}